// Round 1
// 185.263 us; speedup vs baseline: 1.0143x; 1.0143x over previous
//
#include <hip/hip_runtime.h>

#define N_NODES 100000
#define N_EDGES 1600000
#define D 64

// ---- buckets: 128 nodes each ----
#define CSHIFT 7
#define CNODES 128
#define NCB 782             // ceil(100000/128)
#define CAPC 2560           // mean 2048, sigma ~45 -> +11 sigma
#define COLBITS 17
#define COLMASK 0x1FFFF

#define CHUNK 4096
#define EPT 16
#define NCHUNKA 391         // ceil(1600000/4096)

// ws layout (bytes), all 16B aligned
#define CCUR_OFF   0            // int[NCB]            3,128 B
#define CPAIRS_OFF 3200         // int[NCB*CAPC]       8,007,680 B (becomes node-grouped col CSR in-place)
#define RS_OFF     8010880      // int[N_NODES]        400,000 B  (CSR row start, absolute into cpairs)
#define DG_OFF     8410880      // int[N_NODES]        400,000 B  (degree)
#define Y_OFF      8810880      // ushort[N_NODES*D]   12,800,000 B

typedef float fvec4 __attribute__((ext_vector_type(4)));
typedef __attribute__((ext_vector_type(8))) short bf16x8;
typedef __attribute__((ext_vector_type(4))) float f32x4;

__device__ __forceinline__ float bf2f(unsigned short u) {
    return __uint_as_float(((unsigned)u) << 16);
}
__device__ __forceinline__ unsigned f2bf(float f) {
    unsigned bits = __float_as_uint(f);
    return (bits + 0x7FFFu + ((bits >> 16) & 1u)) >> 16;
}

// Pass A: bucket edges by row>>7 into 782 regions, packed (rl7<<17|col).
__global__ __launch_bounds__(256) void scatA_kernel(const int* __restrict__ row,
                                                    const int* __restrict__ col,
                                                    int* __restrict__ ccur,
                                                    int* __restrict__ cpairs) {
    __shared__ int lcnt[NCB];
    int t = threadIdx.x;
    int base = blockIdx.x * CHUNK;
    for (int i = t; i < NCB; i += 256) lcnt[i] = 0;
    __syncthreads();
    int r[EPT], c[EPT], pos[EPT];
#pragma unroll
    for (int i = 0; i < EPT; ++i) {
        int e = base + i * 256 + t;
        if (e < N_EDGES) {
            r[i] = row[e];
            c[i] = col[e];
            pos[i] = atomicAdd(&lcnt[r[i] >> CSHIFT], 1);
        } else r[i] = -1;
    }
    __syncthreads();
    for (int i = t; i < NCB; i += 256) {
        int cc = lcnt[i];
        lcnt[i] = cc ? atomicAdd(&ccur[i], cc) : 0;
    }
    __syncthreads();
#pragma unroll
    for (int i = 0; i < EPT; ++i) {
        if (r[i] >= 0) {
            int cb = r[i] >> CSHIFT;
            int p = lcnt[cb] + pos[i];
            if (p < CAPC)
                cpairs[cb * CAPC + p] = ((r[i] & (CNODES - 1)) << COLBITS) | c[i];
        }
    }
}

// Pass B: one block per bucket. Stage edges in LDS, hist -> scan -> emit CSR
// (rs/dg) and rewrite cpairs in-place grouped by destination node (col only).
__global__ __launch_bounds__(256) void scatB_kernel(const int* __restrict__ ccur,
                                                    int* __restrict__ cpairs,
                                                    int* __restrict__ rs,
                                                    int* __restrict__ dg) {
    __shared__ int epk[CAPC];          // 10,240 B
    __shared__ int hist[CNODES];
    __shared__ int sc[CNODES];
    __shared__ int cur[CNODES];
    int t = threadIdx.x;
    int cb = blockIdx.x;
    int cnt = ccur[cb]; if (cnt > CAPC) cnt = CAPC;
    int base = cb * CAPC;
    if (t < CNODES) hist[t] = 0;
    __syncthreads();
    for (int i = t; i < cnt; i += 256) {
        int p = cpairs[base + i];
        epk[i] = p;
        atomicAdd(&hist[p >> COLBITS], 1);
    }
    __syncthreads();
    if (t < CNODES) sc[t] = hist[t];
    __syncthreads();
    for (int off = 1; off < CNODES; off <<= 1) {
        int v = (t < CNODES && t >= off) ? sc[t - off] : 0;
        __syncthreads();
        if (t < CNODES) sc[t] += v;
        __syncthreads();
    }
    if (t < CNODES) {
        int ex = sc[t] - hist[t];
        cur[t] = ex;
        int n = (cb << CSHIFT) + t;
        if (n < N_NODES) { rs[n] = base + ex; dg[n] = hist[t]; }
    }
    __syncthreads();
    for (int i = t; i < cnt; i += 256) {
        int p = epk[i];
        int pos = atomicAdd(&cur[p >> COLBITS], 1);
        cpairs[base + pos] = p & COLMASK;
    }
}

// y[n] = bf16( dinv[n] * (x[n] @ W^T) ) via bf16 hi/lo split MFMA.
// Per wave: 16 nodes x 64 j. A: lane row = lane&15, k = ks*32 + (lane>>4)*8 + j.
// B symmetric (col = lane&15). C/D: col = lane&15, row = (lane>>4)*4 + reg.
__global__ __launch_bounds__(256) void xform_kernel(
        const float* __restrict__ x, const float* __restrict__ W,
        const int* __restrict__ dg, unsigned short* __restrict__ y) {
    int t = threadIdx.x;
    int wave = t >> 6, lane = t & 63;
    int n0w = blockIdx.x * 64 + wave * 16;
    if (n0w >= N_NODES) return;        // 100000 % 16 == 0: waves all-valid or all-out
    int lm = lane & 15;
    int g  = lane >> 4;

    bf16x8 ahi[2], alo[2];
    const float* xr = x + (size_t)(n0w + lm) * D + g * 8;
#pragma unroll
    for (int ks = 0; ks < 2; ++ks) {
        float4 fa = *(const float4*)(xr + ks * 32);
        float4 fb = *(const float4*)(xr + ks * 32 + 4);
        float f[8] = {fa.x, fa.y, fa.z, fa.w, fb.x, fb.y, fb.z, fb.w};
#pragma unroll
        for (int j = 0; j < 8; ++j) {
            unsigned hb = f2bf(f[j]);
            float r = f[j] - bf2f((unsigned short)hb);
            ahi[ks][j] = (short)hb;
            alo[ks][j] = (short)f2bf(r);
        }
    }
    float dvr[4];
#pragma unroll
    for (int r = 0; r < 4; ++r) {
        int d = dg[n0w + g * 4 + r];
        dvr[r] = (d > 0) ? rsqrtf((float)d) : 0.0f;
    }
#pragma unroll
    for (int jt = 0; jt < 4; ++jt) {
        const float* wr = W + (size_t)(jt * 16 + lm) * D + g * 8;
        bf16x8 whi[2], wlo[2];
#pragma unroll
        for (int ks = 0; ks < 2; ++ks) {
            float4 fa = *(const float4*)(wr + ks * 32);
            float4 fb = *(const float4*)(wr + ks * 32 + 4);
            float f[8] = {fa.x, fa.y, fa.z, fa.w, fb.x, fb.y, fb.z, fb.w};
#pragma unroll
            for (int j = 0; j < 8; ++j) {
                unsigned hb = f2bf(f[j]);
                float r = f[j] - bf2f((unsigned short)hb);
                whi[ks][j] = (short)hb;
                wlo[ks][j] = (short)f2bf(r);
            }
        }
        f32x4 acc = {0.0f, 0.0f, 0.0f, 0.0f};
#pragma unroll
        for (int ks = 0; ks < 2; ++ks) {
            acc = __builtin_amdgcn_mfma_f32_16x16x32_bf16(ahi[ks], whi[ks], acc, 0, 0, 0);
            acc = __builtin_amdgcn_mfma_f32_16x16x32_bf16(alo[ks], whi[ks], acc, 0, 0, 0);
            acc = __builtin_amdgcn_mfma_f32_16x16x32_bf16(ahi[ks], wlo[ks], acc, 0, 0, 0);
        }
#pragma unroll
        for (int r = 0; r < 4; ++r) {
            int n = n0w + g * 4 + r;
            y[(size_t)n * D + jt * 16 + lm] = (unsigned short)f2bf(acc[r] * dvr[r]);
        }
    }
}

// Per 64 nodes: stage contiguous col slab to LDS, gather y rows, butterfly
// reduce over 8 edge slots, scale + bias + relu, NT store. No hist/scan/rebin.
__global__ __launch_bounds__(256) void mega_kernel(
        const int* __restrict__ cols, const int* __restrict__ rs,
        const int* __restrict__ dg, const unsigned short* __restrict__ y,
        const float* __restrict__ bias, float* __restrict__ out) {
    __shared__ int scol[CAPC];         // 64-node slab <= bucket cap
    int t = threadIdx.x;
    int b = blockIdx.x;
    int n0 = b * 64;
    int nlast = n0 + 63; if (nlast >= N_NODES) nlast = N_NODES - 1;
    int base = rs[n0];
    int cnt = rs[nlast] + dg[nlast] - base;
    for (int i = t; i < cnt; i += 256) scol[i] = cols[base + i];
    __syncthreads();
    int wave = t >> 6, lane = t & 63;
    int g = lane >> 3, q = lane & 7;   // g = edge slot, q = feature block (8 bf16)
    float bj[8];
    {
        float4 b0 = *(const float4*)(bias + q * 8);
        float4 b1 = *(const float4*)(bias + q * 8 + 4);
        bj[0] = b0.x; bj[1] = b0.y; bj[2] = b0.z; bj[3] = b0.w;
        bj[4] = b1.x; bj[5] = b1.y; bj[6] = b1.z; bj[7] = b1.w;
    }
#pragma unroll 1
    for (int i = 0; i < 16; ++i) {
        int n = n0 + wave * 16 + i;
        if (n >= N_NODES) break;
        int s = rs[n] - base;
        int d = dg[n];
        float a[8];
#pragma unroll
        for (int j = 0; j < 8; ++j) a[j] = 0.0f;
        for (int k = 0; k < d; k += 32) {
#pragma unroll
            for (int u = 0; u < 4; ++u) {
                int e = k + u * 8 + g;
                if (e < d) {
                    int c = scol[s + e];
                    uint4 v = *(const uint4*)(y + (size_t)c * D + q * 8);
                    a[0] += __uint_as_float(v.x << 16);
                    a[1] += __uint_as_float(v.x & 0xffff0000u);
                    a[2] += __uint_as_float(v.y << 16);
                    a[3] += __uint_as_float(v.y & 0xffff0000u);
                    a[4] += __uint_as_float(v.z << 16);
                    a[5] += __uint_as_float(v.z & 0xffff0000u);
                    a[6] += __uint_as_float(v.w << 16);
                    a[7] += __uint_as_float(v.w & 0xffff0000u);
                }
            }
        }
#pragma unroll
        for (int m = 8; m <= 32; m <<= 1) {
#pragma unroll
            for (int j = 0; j < 8; ++j)
                a[j] += __shfl_xor(a[j], m);
        }
        float dv = (d > 0) ? rsqrtf((float)d) : 0.0f;
        if (g < 2) {
            int o = g * 4;
            fvec4 r;
            r.x = fmaxf(fmaf(dv, a[o + 0], bj[o + 0]), 0.0f);
            r.y = fmaxf(fmaf(dv, a[o + 1], bj[o + 1]), 0.0f);
            r.z = fmaxf(fmaf(dv, a[o + 2], bj[o + 2]), 0.0f);
            r.w = fmaxf(fmaf(dv, a[o + 3], bj[o + 3]), 0.0f);
            __builtin_nontemporal_store(r, (fvec4*)(out + (size_t)n * D + q * 8 + o));
        }
    }
}

extern "C" void kernel_launch(void* const* d_in, const int* in_sizes, int n_in,
                              void* d_out, int out_size, void* d_ws, size_t ws_size,
                              hipStream_t stream) {
    const float* x    = (const float*)d_in[0];
    const int*   eidx = (const int*)d_in[1];
    const float* W    = (const float*)d_in[2];
    const float* b    = (const float*)d_in[3];
    float* out = (float*)d_out;
    char* ws = (char*)d_ws;

    const int* row = eidx;
    const int* col = eidx + N_EDGES;

    int* ccur   = (int*)(ws + CCUR_OFF);
    int* cpairs = (int*)(ws + CPAIRS_OFF);
    int* rs     = (int*)(ws + RS_OFF);
    int* dg     = (int*)(ws + DG_OFF);
    unsigned short* y = (unsigned short*)(ws + Y_OFF);

    hipMemsetAsync(ccur, 0, NCB * sizeof(int), stream);
    scatA_kernel<<<NCHUNKA, 256, 0, stream>>>(row, col, ccur, cpairs);
    scatB_kernel<<<NCB, 256, 0, stream>>>(ccur, cpairs, rs, dg);
    xform_kernel<<<(N_NODES + 63) / 64, 256, 0, stream>>>(x, W, dg, y);
    mega_kernel<<<(N_NODES + 63) / 64, 256, 0, stream>>>(cpairs, rs, dg, y, b, out);
}

// Round 2
// 169.879 us; speedup vs baseline: 1.1062x; 1.0906x over previous
//
#include <hip/hip_runtime.h>

#define N_NODES 100000
#define N_EDGES 1600000
#define D 64

// ---- buckets: 128 nodes each ----
#define CSHIFT 7
#define CNODES 128
#define NCB 782             // ceil(100000/128)
#define CAPC 2560           // mean 2048, sigma ~45 -> +11 sigma
#define COLBITS 17
#define COLMASK 0x1FFFF

#define CHUNKA 2048
#define EPTA 8
#define NCHA 782            // ceil(1600000/2048)
#define XBLKS 1563          // xform blocks (64 nodes each)

// ws layout (bytes), all 16B aligned
#define CCUR_OFF   0            // int[NCB]            3,128 B
#define CPAIRS_OFF 3200         // int[NCB*CAPC]       8,007,680 B (cols CSR after pass B)
#define RS_OFF     8010880      // int[N_NODES]
#define DG_OFF     8410880      // int[N_NODES]
#define DINV_OFF   8810880      // float[N_NODES]
#define Y_OFF      9210880      // ushort[N_NODES*D]   12,800,000 B

typedef float fvec4 __attribute__((ext_vector_type(4)));
typedef __attribute__((ext_vector_type(8))) short bf16x8;
typedef __attribute__((ext_vector_type(4))) float f32x4;

__device__ __forceinline__ float bf2f(unsigned short u) {
    return __uint_as_float(((unsigned)u) << 16);
}
__device__ __forceinline__ unsigned f2bf(float f) {
    unsigned bits = __float_as_uint(f);
    return (bits + 0x7FFFu + ((bits >> 16) & 1u)) >> 16;
}

// Fat kernel: blocks [0,XBLKS) do xform (y = bf16(x@W^T), no dinv -> no dep on
// scatter chain); blocks [XBLKS, XBLKS+NCHA) do scatA (bucket edges by row>>7).
// Independent work overlaps inside one dispatch.
__global__ __launch_bounds__(256) void fat_kernel(
        const float* __restrict__ x, const float* __restrict__ W,
        const int* __restrict__ row, const int* __restrict__ col,
        int* __restrict__ ccur, int* __restrict__ cpairs,
        unsigned short* __restrict__ y) {
    __shared__ int lcnt[NCB];
    int t = threadIdx.x;
    if (blockIdx.x < XBLKS) {
        // ---- xform: per wave 16 nodes x 64 j via bf16 hi/lo split MFMA ----
        int wave = t >> 6, lane = t & 63;
        int n0w = blockIdx.x * 64 + wave * 16;
        if (n0w >= N_NODES) return;    // 100000 % 16 == 0
        int lm = lane & 15;
        int g  = lane >> 4;
        bf16x8 ahi[2], alo[2];
        const float* xr = x + (size_t)(n0w + lm) * D + g * 8;
#pragma unroll
        for (int ks = 0; ks < 2; ++ks) {
            float4 fa = *(const float4*)(xr + ks * 32);
            float4 fb = *(const float4*)(xr + ks * 32 + 4);
            float f[8] = {fa.x, fa.y, fa.z, fa.w, fb.x, fb.y, fb.z, fb.w};
#pragma unroll
            for (int j = 0; j < 8; ++j) {
                unsigned hb = f2bf(f[j]);
                float r = f[j] - bf2f((unsigned short)hb);
                ahi[ks][j] = (short)hb;
                alo[ks][j] = (short)f2bf(r);
            }
        }
#pragma unroll
        for (int jt = 0; jt < 4; ++jt) {
            const float* wr = W + (size_t)(jt * 16 + lm) * D + g * 8;
            bf16x8 whi[2], wlo[2];
#pragma unroll
            for (int ks = 0; ks < 2; ++ks) {
                float4 fa = *(const float4*)(wr + ks * 32);
                float4 fb = *(const float4*)(wr + ks * 32 + 4);
                float f[8] = {fa.x, fa.y, fa.z, fa.w, fb.x, fb.y, fb.z, fb.w};
#pragma unroll
                for (int j = 0; j < 8; ++j) {
                    unsigned hb = f2bf(f[j]);
                    float r = f[j] - bf2f((unsigned short)hb);
                    whi[ks][j] = (short)hb;
                    wlo[ks][j] = (short)f2bf(r);
                }
            }
            f32x4 acc = {0.0f, 0.0f, 0.0f, 0.0f};
#pragma unroll
            for (int ks = 0; ks < 2; ++ks) {
                acc = __builtin_amdgcn_mfma_f32_16x16x32_bf16(ahi[ks], whi[ks], acc, 0, 0, 0);
                acc = __builtin_amdgcn_mfma_f32_16x16x32_bf16(alo[ks], whi[ks], acc, 0, 0, 0);
                acc = __builtin_amdgcn_mfma_f32_16x16x32_bf16(ahi[ks], wlo[ks], acc, 0, 0, 0);
            }
#pragma unroll
            for (int r = 0; r < 4; ++r) {
                int n = n0w + g * 4 + r;
                y[(size_t)n * D + jt * 16 + lm] = (unsigned short)f2bf(acc[r]);
            }
        }
    } else {
        // ---- scatA: bucket 2048 edges into NCB regions, packed (rl7<<17|col) ----
        int base = (blockIdx.x - XBLKS) * CHUNKA;
        for (int i = t; i < NCB; i += 256) lcnt[i] = 0;
        __syncthreads();
        int r[EPTA], c[EPTA], pos[EPTA];
#pragma unroll
        for (int i = 0; i < EPTA; ++i) {
            int e = base + i * 256 + t;
            if (e < N_EDGES) {
                r[i] = row[e];
                c[i] = col[e];
                pos[i] = atomicAdd(&lcnt[r[i] >> CSHIFT], 1);
            } else r[i] = -1;
        }
        __syncthreads();
        for (int i = t; i < NCB; i += 256) {
            int cc = lcnt[i];
            lcnt[i] = cc ? atomicAdd(&ccur[i], cc) : 0;
        }
        __syncthreads();
#pragma unroll
        for (int i = 0; i < EPTA; ++i) {
            if (r[i] >= 0) {
                int cb = r[i] >> CSHIFT;
                int p = lcnt[cb] + pos[i];
                if (p < CAPC)
                    cpairs[cb * CAPC + p] = ((r[i] & (CNODES - 1)) << COLBITS) | c[i];
            }
        }
    }
}

// Pass B: one block per bucket. Stage edges in LDS, hist -> scan -> emit CSR
// (rs/dg/dinv) and rewrite cpairs in-place grouped by node (col only).
__global__ __launch_bounds__(512) void scatB_kernel(const int* __restrict__ ccur,
                                                    int* __restrict__ cpairs,
                                                    int* __restrict__ rs,
                                                    int* __restrict__ dg,
                                                    float* __restrict__ dinv) {
    __shared__ int epk[CAPC];
    __shared__ int hist[CNODES];
    __shared__ int sc[CNODES];
    __shared__ int cur[CNODES];
    int t = threadIdx.x;
    int cb = blockIdx.x;
    int cnt = ccur[cb]; if (cnt > CAPC) cnt = CAPC;
    int base = cb * CAPC;
    if (t < CNODES) hist[t] = 0;
    __syncthreads();
    for (int i = t; i < cnt; i += 512) {
        int p = cpairs[base + i];
        epk[i] = p;
        atomicAdd(&hist[p >> COLBITS], 1);
    }
    __syncthreads();
    if (t < CNODES) sc[t] = hist[t];
    __syncthreads();
    for (int off = 1; off < CNODES; off <<= 1) {
        int v = (t < CNODES && t >= off) ? sc[t - off] : 0;
        __syncthreads();
        if (t < CNODES) sc[t] += v;
        __syncthreads();
    }
    if (t < CNODES) {
        int ex = sc[t] - hist[t];
        cur[t] = ex;
        int n = (cb << CSHIFT) + t;
        if (n < N_NODES) {
            rs[n] = base + ex;
            dg[n] = hist[t];
            dinv[n] = (hist[t] > 0) ? rsqrtf((float)hist[t]) : 0.0f;
        }
    }
    __syncthreads();
    for (int i = t; i < cnt; i += 512) {
        int p = epk[i];
        int pos = atomicAdd(&cur[p >> COLBITS], 1);
        cpairs[base + pos] = p & COLMASK;
    }
}

// Gather: lane owns (node-slot g, feat-block q). No LDS, no barrier, no
// butterfly. Per lane: serial edge loop, 4-edge unroll, col loads software-
// pipelined one iteration ahead; dinv_src folded into the fma. Every lane
// stores 32B of its node's output row.
__global__ __launch_bounds__(256) void mega_kernel(
        const int* __restrict__ cols, const int* __restrict__ rs,
        const int* __restrict__ dg, const float* __restrict__ dinv,
        const unsigned short* __restrict__ y,
        const float* __restrict__ bias, float* __restrict__ out) {
    int t = threadIdx.x;
    int wave = t >> 6, lane = t & 63;
    int g = lane >> 3, q = lane & 7;
    int n = blockIdx.x * 32 + wave * 8 + g;   // grid 3125 -> exactly N_NODES
    int s = rs[n], d = dg[n];
    float bj[8];
    {
        float4 b0 = *(const float4*)(bias + q * 8);
        float4 b1 = *(const float4*)(bias + q * 8 + 4);
        bj[0] = b0.x; bj[1] = b0.y; bj[2] = b0.z; bj[3] = b0.w;
        bj[4] = b1.x; bj[5] = b1.y; bj[6] = b1.z; bj[7] = b1.w;
    }
    float a[8];
#pragma unroll
    for (int j = 0; j < 8; ++j) a[j] = 0.0f;
    int c4[4];
#pragma unroll
    for (int u = 0; u < 4; ++u) c4[u] = (u < d) ? cols[s + u] : 0;
    for (int k = 0; k < d; k += 4) {
        uint4 v[4];
        float dvl[4];
#pragma unroll
        for (int u = 0; u < 4; ++u) {
            if (k + u < d) {
                int c = c4[u];
                dvl[u] = dinv[c];
                v[u] = *(const uint4*)(y + (size_t)c * D + q * 8);
            }
        }
#pragma unroll
        for (int u = 0; u < 4; ++u) {
            int e2 = k + 4 + u;
            c4[u] = (e2 < d) ? cols[s + e2] : 0;
        }
#pragma unroll
        for (int u = 0; u < 4; ++u) {
            if (k + u < d) {
                float dvu = dvl[u];
                a[0] = fmaf(dvu, __uint_as_float(v[u].x << 16),        a[0]);
                a[1] = fmaf(dvu, __uint_as_float(v[u].x & 0xffff0000u), a[1]);
                a[2] = fmaf(dvu, __uint_as_float(v[u].y << 16),        a[2]);
                a[3] = fmaf(dvu, __uint_as_float(v[u].y & 0xffff0000u), a[3]);
                a[4] = fmaf(dvu, __uint_as_float(v[u].z << 16),        a[4]);
                a[5] = fmaf(dvu, __uint_as_float(v[u].z & 0xffff0000u), a[5]);
                a[6] = fmaf(dvu, __uint_as_float(v[u].w << 16),        a[6]);
                a[7] = fmaf(dvu, __uint_as_float(v[u].w & 0xffff0000u), a[7]);
            }
        }
    }
    float dvn = dinv[n];
    fvec4 r0, r1;
    r0.x = fmaxf(fmaf(dvn, a[0], bj[0]), 0.0f);
    r0.y = fmaxf(fmaf(dvn, a[1], bj[1]), 0.0f);
    r0.z = fmaxf(fmaf(dvn, a[2], bj[2]), 0.0f);
    r0.w = fmaxf(fmaf(dvn, a[3], bj[3]), 0.0f);
    r1.x = fmaxf(fmaf(dvn, a[4], bj[4]), 0.0f);
    r1.y = fmaxf(fmaf(dvn, a[5], bj[5]), 0.0f);
    r1.z = fmaxf(fmaf(dvn, a[6], bj[6]), 0.0f);
    r1.w = fmaxf(fmaf(dvn, a[7], bj[7]), 0.0f);
    __builtin_nontemporal_store(r0, (fvec4*)(out + (size_t)n * D + q * 8));
    __builtin_nontemporal_store(r1, (fvec4*)(out + (size_t)n * D + q * 8 + 4));
}

extern "C" void kernel_launch(void* const* d_in, const int* in_sizes, int n_in,
                              void* d_out, int out_size, void* d_ws, size_t ws_size,
                              hipStream_t stream) {
    const float* x    = (const float*)d_in[0];
    const int*   eidx = (const int*)d_in[1];
    const float* W    = (const float*)d_in[2];
    const float* b    = (const float*)d_in[3];
    float* out = (float*)d_out;
    char* ws = (char*)d_ws;

    const int* row = eidx;
    const int* col = eidx + N_EDGES;

    int* ccur   = (int*)(ws + CCUR_OFF);
    int* cpairs = (int*)(ws + CPAIRS_OFF);
    int* rs     = (int*)(ws + RS_OFF);
    int* dg     = (int*)(ws + DG_OFF);
    float* dinv = (float*)(ws + DINV_OFF);
    unsigned short* y = (unsigned short*)(ws + Y_OFF);

    hipMemsetAsync(ccur, 0, NCB * sizeof(int), stream);
    fat_kernel<<<XBLKS + NCHA, 256, 0, stream>>>(x, W, row, col, ccur, cpairs, y);
    scatB_kernel<<<NCB, 512, 0, stream>>>(ccur, cpairs, rs, dg, dinv);
    mega_kernel<<<3125, 256, 0, stream>>>(cpairs, rs, dg, dinv, y, b, out);
}